// Round 2
// baseline (224.145 us; speedup 1.0000x reference)
//
#include <hip/hip_runtime.h>
#include <hip/hip_bf16.h>
#include <math.h>

typedef __attribute__((ext_vector_type(8))) short short8;
typedef __attribute__((ext_vector_type(4))) float f32x4;
typedef __attribute__((ext_vector_type(4))) short short4v;
typedef __attribute__((ext_vector_type(2))) int int2v;

static __device__ __forceinline__ short f2bf(float f) {
    __hip_bfloat16 h = __float2bfloat16(f);
    return *reinterpret_cast<short*>(&h);
}
static __device__ __forceinline__ void store_out(float* p, float v) { *p = v; }
static __device__ __forceinline__ void store_out(short* p, float v) { *p = f2bf(v); }

#define GLL16(g, l) __builtin_amdgcn_global_load_lds( \
    (const __attribute__((address_space(1))) void*)(g), \
    (__attribute__((address_space(3))) void*)(l), 16, 0, 0)

#if __has_builtin(__builtin_amdgcn_exp2f)
#define EXP2(x) __builtin_amdgcn_exp2f(x)
#else
#define EXP2(x) exp2f(x)
#endif

// pack two f32 -> packed bf16 pair (low = a, high = b)
#if __has_builtin(__builtin_amdgcn_cvt_pk_bf16_f32)
typedef __attribute__((ext_vector_type(2))) __bf16 bf16x2;
static __device__ __forceinline__ int pack2bf(float a, float b) {
    bf16x2 r = __builtin_amdgcn_cvt_pk_bf16_f32(a, b);
    return __builtin_bit_cast(int, r);
}
#else
static __device__ __forceinline__ int pack2bf(float a, float b) {
    unsigned ua = __builtin_bit_cast(unsigned, a) + 0x8000u;
    unsigned ub = __builtin_bit_cast(unsigned, b) + 0x8000u;
    return (int)((ua >> 16) | (ub & 0xFFFF0000u));
}
#endif

// ---------------- fused prep: cast x -> bf16; transpose+cast both weights ----
static __device__ __forceinline__ void transpose_cast_tile(
    const float* __restrict__ W, short* __restrict__ Wt, int Kd, int N,
    int bx, int by)
{
    __shared__ float ts[32][33];
    const int c0 = bx * 32, r0 = by * 32;
    const int tx = threadIdx.x & 31, ty = threadIdx.x >> 5;   // ty 0..7
    #pragma unroll
    for (int e = 0; e < 4; ++e)
        ts[ty + e * 8][tx] = W[(size_t)(r0 + ty + e * 8) * N + c0 + tx];
    __syncthreads();
    #pragma unroll
    for (int e = 0; e < 4; ++e)
        Wt[(size_t)(c0 + ty + e * 8) * Kd + r0 + tx] = f2bf(ts[tx][ty + e * 8]);
}

__global__ __launch_bounds__(256) void prep_kernel(
    const float* __restrict__ x,      short* __restrict__ xb,    int nx,
    const float* __restrict__ W_qkv,  short* __restrict__ Wt1,
    const float* __restrict__ W_proj, short* __restrict__ Wt2,
    int C)
{
    const int nbx = nx / 1024;
    const int nb1 = (3 * C / 32) * (C / 32);
    int bid = blockIdx.x;
    if (bid < nbx) {
        int i = (bid * 256 + threadIdx.x) * 4;
        float4 v = *(const float4*)(x + i);
        short4v o = { f2bf(v.x), f2bf(v.y), f2bf(v.z), f2bf(v.w) };
        *(short4v*)(xb + i) = o;
        return;
    }
    bid -= nbx;
    if (bid < nb1) {
        const int nc = 3 * C / 32;
        transpose_cast_tile(W_qkv, Wt1, C, 3 * C, bid % nc, bid / nc);
        return;
    }
    bid -= nb1;
    {
        const int nc = C / 32;
        transpose_cast_tile(W_proj, Wt2, C, C, bid % nc, bid / nc);
    }
}

// ---------------- V transpose: qkv [B,K,3C] -> Vt [B,H,DH,K] (bf16) ----------------
__global__ __launch_bounds__(256) void vtrans_kernel(
    const short* __restrict__ qkvb, short* __restrict__ vt, int K, int C)
{
    __shared__ short Vs[64][72];
    const int k0 = blockIdx.x * 64, h = blockIdx.y, b = blockIdx.z;
    const size_t rs = (size_t)3 * C;
    const short* src = qkvb + (size_t)b * K * rs + 2 * C + h * 64;
    const int key = threadIdx.x >> 3, d0 = (threadIdx.x & 7) * 8;
    *(short8*)&Vs[key][d0]      = *(const short8*)(src + (size_t)(k0 + key) * rs + d0);
    *(short8*)&Vs[key + 32][d0] = *(const short8*)(src + (size_t)(k0 + key + 32) * rs + d0);
    __syncthreads();
    const int d = threadIdx.x >> 2, kc = threadIdx.x & 3;
    short* dst = vt + ((size_t)(b * 16 + h) * 64 + d) * K + k0 + kc * 16;
    short8 o0, o1;
    #pragma unroll
    for (int j = 0; j < 8; ++j) { o0[j] = Vs[kc * 16 + j][d]; o1[j] = Vs[kc * 16 + 8 + j][d]; }
    *(short8*)dst = o0;
    *(short8*)(dst + 8) = o1;
}

// ---------------- MFMA bf16 GEMM (m97 structure): C = A @ Bt^T + bias --------
// Columns c < qcols get an extra *qscale (folds softmax scale into Q).
#define GM 128
#define GN 128
#define GK 32

template <typename OutT>
__global__ __launch_bounds__(256) void gemm_mfma_kernel(
    const short* __restrict__ A, const short* __restrict__ Bt,
    const float* __restrict__ bias, OutT* __restrict__ C,
    int M, int N, int Kd, int qcols, float qscale)
{
    __shared__ __attribute__((aligned(16))) short As[GM * GK];
    __shared__ __attribute__((aligned(16))) short Bs[GN * GK];
    const int tid  = threadIdx.x;
    const int lane = tid & 63, w = tid >> 6;
    const int col  = lane & 15, quad = lane >> 4;
    const int wm = (w & 1) * 64, wn = (w >> 1) * 64;
    const int row0 = blockIdx.y * GM, col0 = blockIdx.x * GN;
    const float sc = (col0 < qcols) ? qscale : 1.f;

    const int sr = tid >> 2, scg = (tid & 3) * 8;
    const short* gA = A  + (size_t)(row0 + sr) * Kd + scg;
    const short* gB = Bt + (size_t)(col0 + sr) * Kd + scg;
    short* lA = As + sr * GK + scg;
    short* lB = Bs + sr * GK + scg;
    const size_t skip = (size_t)64 * Kd;

    f32x4 acc[4][4] = {};
    for (int k0 = 0; k0 < Kd; k0 += GK) {
        __syncthreads();
        GLL16(gA,        lA);
        GLL16(gA + skip, lA + 64 * GK);
        GLL16(gB,        lB);
        GLL16(gB + skip, lB + 64 * GK);
        gA += GK; gB += GK;
        __syncthreads();

        short8 aF[4], bF[4];
        #pragma unroll
        for (int mt = 0; mt < 4; ++mt)
            aF[mt] = *(const short8*)&As[(wm + mt * 16 + col) * GK + quad * 8];
        #pragma unroll
        for (int nt = 0; nt < 4; ++nt)
            bF[nt] = *(const short8*)&Bs[(wn + nt * 16 + col) * GK + quad * 8];
        #pragma unroll
        for (int mt = 0; mt < 4; ++mt)
            #pragma unroll
            for (int nt = 0; nt < 4; ++nt)
                acc[mt][nt] = __builtin_amdgcn_mfma_f32_16x16x32_bf16(aF[mt], bF[nt], acc[mt][nt], 0, 0, 0);
    }

    #pragma unroll
    for (int mt = 0; mt < 4; ++mt)
        #pragma unroll
        for (int i = 0; i < 4; ++i) {
            const size_t r = row0 + wm + mt * 16 + quad * 4 + i;
            #pragma unroll
            for (int nt = 0; nt < 4; ++nt) {
                const int c = col0 + wn + nt * 16 + col;
                store_out(&C[r * N + c], (acc[mt][nt][i] + bias[c]) * sc);
            }
        }
}

// ---------------- MFMA flash attention — independent 1-wave blocks ----------
// Key insight: the old K/V LDS staging was WAVE-PRIVATE pure lane-rearrangement.
// Per-lane global addresses are unconstrained, so each lane now loads EXACTLY
// its MFMA fragment bytes straight from global (K: 16B of row key=2col+nb at
// dh=half*32+quad*8; V: 16B of the vt row d=db*16+col) -- no LDS staging, no
// store_chunk, no lgkm round-trip for K/V at all. Double-buffered register
// fragment sets (fA/fB, static indexing only -- rule #20) prefetch one 32-key
// chunk ahead; the load->MFMA dependency is plain register dataflow.
//
// Structure: ONE WAVE = one (b, h, 32-q tile). No split-K, no cross-wave
// reduction, ZERO barriers. Grid = 64 tiles x 32 (b,h) = 2048 one-wave blocks,
// heavy-first (T descending) so the scheduler backfills short tiles behind
// long ones. blockIdx%8 == h%8 clusters each head's K/V on one XCD
// (~2MB working set, fits 4MB L2). Per-tile chunks = T+1; only the diagonal
// chunk is masked. LDS = P round-trip (2x640sh) + output-pack staging
// (32x68 f32) = 11.3 KB/block. __launch_bounds__(64,3) targets 3 waves/SIMD
// (12 blocks/CU) vs the previous structure's 2. T5 setprio(1) wraps the
// MFMA/exp cluster (m191: +4-7% on independent-wave attention).
//
// Fixed-shift softmax (Q pre-scaled by scale*log2e in GEMM1): p = exp2(s);
// row-sums ride the MFMA pipe (ones-column fragment).
#define DH 64

__global__ __launch_bounds__(64, 3) void flash_mfma_kernel(
    const short* __restrict__ qkvb,   // bf16 [B,K,3C] (Q pre-scaled)
    const short* __restrict__ vt,     // bf16 [B,H,DH,K]
    short* __restrict__ y,            // bf16 [B,K,C]
    int K, int C)
{
    __shared__ __attribute__((aligned(16))) short Pbuf[2 * 640];  // per-qg P
    __shared__ __attribute__((aligned(16))) float Ow[32 * 68];    // out staging

    const int lane = threadIdx.x & 63;
    const int col  = lane & 15, quad = lane >> 4;

    const int cmb = blockIdx.x & 31;        // b*16+h  (idx%8 = h%8 -> XCD-local)
    const int T   = 63 - (blockIdx.x >> 5); // heavy tiles dispatch first
    const int b   = cmb >> 4, h = cmb & 15;
    const int t0  = T * 32;
    const int NC  = T + 1;                  // 32-key chunks (only last is masked)

    short8 bOnes;                           // L = P @ ones-column = rowsum
    #pragma unroll
    for (int j = 0; j < 8; ++j) bOnes[j] = (col == 0) ? (short)0x3F80 : (short)0;

    const size_t rs = (size_t)3 * C;
    const short* qbase = qkvb + (size_t)b * K * rs + h * DH;
    const short* kbase = qbase + C;
    const short* vbase = vt + (size_t)(b * 16 + h) * DH * K;

    // Q fragments: A[row=q=t0+qg*16+col][dh=half*32+quad*8 ..+8]
    short8 aQ[2][2];
    #pragma unroll
    for (int qg = 0; qg < 2; ++qg) {
        const short* qp = qbase + (size_t)(t0 + qg * 16 + col) * rs + quad * 8;
        aQ[qg][0] = *(const short8*)(qp);
        aQ[qg][1] = *(const short8*)(qp + 32);
    }

    // per-lane fragment bases (chunk offset added per load)
    const short* kfrag = kbase + (size_t)(2 * col) * rs + quad * 8;
    const short* vfrag = vbase + (size_t)col * K + quad * 8;

    struct Frag { short8 k[2][2]; short8 v[4]; };
    auto loadF = [&](Frag& f, int ci) {
        const size_t ko = (size_t)ci * 32 * rs;
        #pragma unroll
        for (int nb = 0; nb < 2; ++nb) {
            f.k[nb][0] = *(const short8*)(kfrag + ko + (size_t)nb * rs);
            f.k[nb][1] = *(const short8*)(kfrag + ko + (size_t)nb * rs + 32);
        }
        const int kc = ci * 32;
        #pragma unroll
        for (int db = 0; db < 4; ++db)
            f.v[db] = *(const short8*)(vfrag + (size_t)(db * 16) * K + kc);
    };

    f32x4 O[2][4] = {};
    f32x4 L4[2] = {};

    auto compute = [&](const Frag& f, int ci) {
        const int kc = ci * 32;
        __builtin_amdgcn_s_setprio(1);
        #pragma unroll
        for (int qg = 0; qg < 2; ++qg) {
            const int qb = t0 + qg * 16;
            short* Ptq = Pbuf + qg * 640;
            f32x4 S[2] = {};
            #pragma unroll
            for (int nb = 0; nb < 2; ++nb) {
                S[nb] = __builtin_amdgcn_mfma_f32_16x16x32_bf16(aQ[qg][0], f.k[nb][0], S[nb], 0, 0, 0);
                S[nb] = __builtin_amdgcn_mfma_f32_16x16x32_bf16(aQ[qg][1], f.k[nb][1], S[nb], 0, 0, 0);
            }
            if (kc + 31 <= qb) {            // fully unmasked (all chunks but last)
                #pragma unroll
                for (int i = 0; i < 4; ++i)
                    *(int*)&Ptq[(quad * 4 + i) * 40 + col * 2] =
                        pack2bf(EXP2(S[0][i]), EXP2(S[1][i]));
            } else {
                const int kg = kc + col * 2;
                #pragma unroll
                for (int i = 0; i < 4; ++i) {
                    const int q = qb + quad * 4 + i;
                    float s0 = (kg + 0 <= q) ? S[0][i] : -INFINITY;
                    float s1 = (kg + 1 <= q) ? S[1][i] : -INFINITY;
                    *(int*)&Ptq[(quad * 4 + i) * 40 + col * 2] =
                        pack2bf(EXP2(s0), EXP2(s1));
                }
            }
            // compiler inserts the minimal lgkmcnt for this buffer's RAW
            short8 aP = *(const short8*)&Ptq[col * 40 + quad * 8];
            #pragma unroll
            for (int db = 0; db < 4; ++db)
                O[qg][db] = __builtin_amdgcn_mfma_f32_16x16x32_bf16(aP, f.v[db], O[qg][db], 0, 0, 0);
            L4[qg] = __builtin_amdgcn_mfma_f32_16x16x32_bf16(aP, bOnes, L4[qg], 0, 0, 0);
        }
        __builtin_amdgcn_s_setprio(0);
    };

    // ---- main loop: double-buffered register fragments, prefetch 1 ahead ----
    Frag fA, fB;
    loadF(fA, 0);
    for (int ci = 0; ci < NC; ci += 2) {
        if (ci + 1 < NC) loadF(fB, ci + 1);
        compute(fA, ci);
        if (ci + 1 < NC) {
            if (ci + 2 < NC) loadF(fA, ci + 2);
            compute(fB, ci + 1);
        }
    }

    // ---- epilogue: stage to LDS, normalize, packed 8B stores (no barriers) ----
    #pragma unroll
    for (int qg = 0; qg < 2; ++qg)
        #pragma unroll
        for (int i = 0; i < 4; ++i) {
            const int row = qg * 16 + quad * 4 + i;
            #pragma unroll
            for (int db = 0; db < 4; ++db)
                Ow[row * 68 + db * 16 + col] = O[qg][db][i];
            if (col == 0) Ow[row * 68 + 64] = L4[qg][i];
        }
    #pragma unroll
    for (int rstep = 0; rstep < 8; ++rstep) {
        const int row = rstep * 4 + quad;
        f32x4 o = *(const f32x4*)&Ow[row * 68 + col * 4];
        const float inv = 1.f / Ow[row * 68 + 64];
        int2v o2 = { pack2bf(o[0] * inv, o[1] * inv),
                     pack2bf(o[2] * inv, o[3] * inv) };
        *(int2v*)(y + ((size_t)b * K + t0 + row) * C + h * DH + col * 4) = o2;
    }
}

// ------------------------------- launch -------------------------------------
extern "C" void kernel_launch(void* const* d_in, const int* in_sizes, int n_in,
                              void* d_out, int out_size, void* d_ws, size_t ws_size,
                              hipStream_t stream)
{
    const float* x      = (const float*)d_in[0];
    const float* W_qkv  = (const float*)d_in[1];
    const float* b_qkv  = (const float*)d_in[2];
    const float* W_proj = (const float*)d_in[3];
    const float* b_proj = (const float*)d_in[4];

    const int B = 2, K = 2048, C = 1024, H = 16;
    const int M = B * K;   // 4096
    const float C2 = 0.18033688f;   // (1/sqrt(64)) * log2(e)

    char* ws = (char*)d_ws;
    short* xb    = (short*)ws;  ws += (size_t)M * C * 2;
    short* Wt1   = (short*)ws;  ws += (size_t)3 * C * C * 2;
    short* Wt2   = (short*)ws;  ws += (size_t)C * C * 2;
    short* qkvb  = (short*)ws;  ws += (size_t)M * 3 * C * 2;
    short* yb    = (short*)ws;  ws += (size_t)M * C * 2;
    short* vtb   = (short*)ws;

    // prep (fused): cast x + transpose both weights
    const int nbx = (M * C) / 1024;
    const int nb1 = (3 * C / 32) * (C / 32);
    const int nb2 = (C / 32) * (C / 32);
    prep_kernel<<<nbx + nb1 + nb2, 256, 0, stream>>>(x, xb, M * C, W_qkv, Wt1, W_proj, Wt2, C);

    // 1) qkv = x @ W_qkv + b_qkv  (bf16 out; Q columns pre-scaled by C2)
    dim3 g1((3 * C) / GN, M / GM);
    gemm_mfma_kernel<short><<<g1, 256, 0, stream>>>(xb, Wt1, b_qkv, qkvb, M, 3 * C, C, C, C2);

    // 1b) V transpose for flash B-fragments
    dim3 gv(K / 64, H, B);
    vtrans_kernel<<<gv, 256, 0, stream>>>(qkvb, vtb, K, C);

    // 2) flash attention -> yb (bf16); 1-wave blocks: idx = tile_rev*32 + (b*16+h)
    flash_mfma_kernel<<<dim3(64 * 32), 64, 0, stream>>>(qkvb, vtb, yb, K, C);

    // 3) out = y @ W_proj + b_proj (fp32 out)
    dim3 g3(C / GN, M / GM);
    gemm_mfma_kernel<float><<<g3, 256, 0, stream>>>(yb, Wt2, b_proj, (float*)d_out, M, C, C, 0, 1.f);
}

// Round 3
// 185.343 us; speedup vs baseline: 1.2094x; 1.2094x over previous
//
#include <hip/hip_runtime.h>
#include <hip/hip_bf16.h>
#include <math.h>

typedef __attribute__((ext_vector_type(8))) short short8;
typedef __attribute__((ext_vector_type(4))) float f32x4;
typedef __attribute__((ext_vector_type(4))) short short4v;
typedef __attribute__((ext_vector_type(2))) int int2v;

static __device__ __forceinline__ short f2bf(float f) {
    __hip_bfloat16 h = __float2bfloat16(f);
    return *reinterpret_cast<short*>(&h);
}
static __device__ __forceinline__ void store_out(float* p, float v) { *p = v; }
static __device__ __forceinline__ void store_out(short* p, float v) { *p = f2bf(v); }

#define GLL16(g, l) __builtin_amdgcn_global_load_lds( \
    (const __attribute__((address_space(1))) void*)(g), \
    (__attribute__((address_space(3))) void*)(l), 16, 0, 0)

#if __has_builtin(__builtin_amdgcn_exp2f)
#define EXP2(x) __builtin_amdgcn_exp2f(x)
#else
#define EXP2(x) exp2f(x)
#endif

// pack two f32 -> packed bf16 pair (low = a, high = b)
#if __has_builtin(__builtin_amdgcn_cvt_pk_bf16_f32)
typedef __attribute__((ext_vector_type(2))) __bf16 bf16x2;
static __device__ __forceinline__ int pack2bf(float a, float b) {
    bf16x2 r = __builtin_amdgcn_cvt_pk_bf16_f32(a, b);
    return __builtin_bit_cast(int, r);
}
#else
static __device__ __forceinline__ int pack2bf(float a, float b) {
    unsigned ua = __builtin_bit_cast(unsigned, a) + 0x8000u;
    unsigned ub = __builtin_bit_cast(unsigned, b) + 0x8000u;
    return (int)((ua >> 16) | (ub & 0xFFFF0000u));
}
#endif

// ---------------- fused prep: cast x -> bf16; transpose+cast both weights ----
static __device__ __forceinline__ void transpose_cast_tile(
    const float* __restrict__ W, short* __restrict__ Wt, int Kd, int N,
    int bx, int by)
{
    __shared__ float ts[32][33];
    const int c0 = bx * 32, r0 = by * 32;
    const int tx = threadIdx.x & 31, ty = threadIdx.x >> 5;   // ty 0..7
    #pragma unroll
    for (int e = 0; e < 4; ++e)
        ts[ty + e * 8][tx] = W[(size_t)(r0 + ty + e * 8) * N + c0 + tx];
    __syncthreads();
    #pragma unroll
    for (int e = 0; e < 4; ++e)
        Wt[(size_t)(c0 + ty + e * 8) * Kd + r0 + tx] = f2bf(ts[tx][ty + e * 8]);
}

__global__ __launch_bounds__(256) void prep_kernel(
    const float* __restrict__ x,      short* __restrict__ xb,    int nx,
    const float* __restrict__ W_qkv,  short* __restrict__ Wt1,
    const float* __restrict__ W_proj, short* __restrict__ Wt2,
    int C)
{
    const int nbx = nx / 1024;
    const int nb1 = (3 * C / 32) * (C / 32);
    int bid = blockIdx.x;
    if (bid < nbx) {
        int i = (bid * 256 + threadIdx.x) * 4;
        float4 v = *(const float4*)(x + i);
        short4v o = { f2bf(v.x), f2bf(v.y), f2bf(v.z), f2bf(v.w) };
        *(short4v*)(xb + i) = o;
        return;
    }
    bid -= nbx;
    if (bid < nb1) {
        const int nc = 3 * C / 32;
        transpose_cast_tile(W_qkv, Wt1, C, 3 * C, bid % nc, bid / nc);
        return;
    }
    bid -= nb1;
    {
        const int nc = C / 32;
        transpose_cast_tile(W_proj, Wt2, C, C, bid % nc, bid / nc);
    }
}

// ---------------- KV fragment pack --------------------------------------------
// qkv [B,K,3C] -> kvp[bh][ci][frag 0..7][lane*8sh], 16B per (frag,lane):
//   frag 0..3 (K, nb=f>>1 half=f&1): lane(col,quad) = K[kc+2*col+nb][quad*8+half*32 ..+8]
//   frag 4..7 (V, db=f-4):           lane(col,quad) = V[kc+quad*8..+8][db*16+col] (transposed)
// This is exactly the per-lane MFMA fragment byte-set the flash kernel consumes,
// so the flash K/V loads become single fully-coalesced dwordx4 (consecutive 1KB
// lines) straight into registers -- no LDS staging in the hot kernel at all.
// Round-2 lesson: per-lane DIRECT fragment loads from the [K,3C] layout are
// address-divergent (32 rows x 16B per instruction = ~32 transactions); doing
// the permutation once here (global->LDS->global, both sides coalesced) costs
// ~33MB of traffic (~5us) and makes the hot-loop loads 1-transaction each.
__global__ __launch_bounds__(256) void kvpack_kernel(
    const short* __restrict__ qkvb, short* __restrict__ kvp, int K, int C)
{
    __shared__ __attribute__((aligned(16))) short Ks[64][80];  // 160B rows: b128-aligned
    __shared__ __attribute__((aligned(16))) short Vs[64][76];  // 152B rows: 4-way-spread col reads
    const int k0 = blockIdx.x * 64, h = blockIdx.y, b = blockIdx.z;
    const size_t rs = (size_t)3 * C;
    const short* kb = qkvb + (size_t)b * K * rs + C + h * 64;
    const short* vb = qkvb + (size_t)b * K * rs + 2 * C + h * 64;
    const int key = threadIdx.x >> 3, d0 = (threadIdx.x & 7) * 8;

    *(short8*)&Ks[key][d0]      = *(const short8*)(kb + (size_t)(k0 + key) * rs + d0);
    *(short8*)&Ks[key + 32][d0] = *(const short8*)(kb + (size_t)(k0 + key + 32) * rs + d0);
    short8 v0 = *(const short8*)(vb + (size_t)(k0 + key) * rs + d0);
    short8 v1 = *(const short8*)(vb + (size_t)(k0 + key + 32) * rs + d0);
    *(short4v*)&Vs[key][d0]          = __builtin_shufflevector(v0, v0, 0, 1, 2, 3);
    *(short4v*)&Vs[key][d0 + 4]      = __builtin_shufflevector(v0, v0, 4, 5, 6, 7);
    *(short4v*)&Vs[key + 32][d0]     = __builtin_shufflevector(v1, v1, 0, 1, 2, 3);
    *(short4v*)&Vs[key + 32][d0 + 4] = __builtin_shufflevector(v1, v1, 4, 5, 6, 7);
    __syncthreads();

    const int bh = b * 16 + h;
    #pragma unroll
    for (int ss = 0; ss < 2; ++ss) {
        const int s    = threadIdx.x + ss * 256;       // 0..511
        const int ci_l = s >> 8, f = (s >> 6) & 3, lane = s & 63;
        const int col  = lane & 15, quad = lane >> 4;
        const int ci   = (k0 >> 5) + ci_l;
        const size_t cb = ((size_t)bh * 64 + ci) * 4096;
        {   // K fragment: contiguous short8 in Ks
            const int nb = f >> 1, half = f & 1;
            short8 d = *(const short8*)&Ks[ci_l * 32 + 2 * col + nb][quad * 8 + half * 32];
            *(short8*)(kvp + cb + (size_t)f * 512 + lane * 8) = d;
        }
        {   // V fragment: column gather (transpose) from Vs
            const int db = f;
            short8 d;
            #pragma unroll
            for (int j = 0; j < 8; ++j)
                d[j] = Vs[ci_l * 32 + quad * 8 + j][db * 16 + col];
            *(short8*)(kvp + cb + (size_t)(4 + db) * 512 + lane * 8) = d;
        }
    }
}

// ---------------- MFMA bf16 GEMM (m97 structure): C = A @ Bt^T + bias --------
// Columns c < qcols get an extra *qscale (folds softmax scale into Q).
#define GM 128
#define GN 128
#define GK 32

template <typename OutT>
__global__ __launch_bounds__(256) void gemm_mfma_kernel(
    const short* __restrict__ A, const short* __restrict__ Bt,
    const float* __restrict__ bias, OutT* __restrict__ C,
    int M, int N, int Kd, int qcols, float qscale)
{
    __shared__ __attribute__((aligned(16))) short As[GM * GK];
    __shared__ __attribute__((aligned(16))) short Bs[GN * GK];
    const int tid  = threadIdx.x;
    const int lane = tid & 63, w = tid >> 6;
    const int col  = lane & 15, quad = lane >> 4;
    const int wm = (w & 1) * 64, wn = (w >> 1) * 64;
    const int row0 = blockIdx.y * GM, col0 = blockIdx.x * GN;
    const float sc = (col0 < qcols) ? qscale : 1.f;

    const int sr = tid >> 2, scg = (tid & 3) * 8;
    const short* gA = A  + (size_t)(row0 + sr) * Kd + scg;
    const short* gB = Bt + (size_t)(col0 + sr) * Kd + scg;
    short* lA = As + sr * GK + scg;
    short* lB = Bs + sr * GK + scg;
    const size_t skip = (size_t)64 * Kd;

    f32x4 acc[4][4] = {};
    for (int k0 = 0; k0 < Kd; k0 += GK) {
        __syncthreads();
        GLL16(gA,        lA);
        GLL16(gA + skip, lA + 64 * GK);
        GLL16(gB,        lB);
        GLL16(gB + skip, lB + 64 * GK);
        gA += GK; gB += GK;
        __syncthreads();

        short8 aF[4], bF[4];
        #pragma unroll
        for (int mt = 0; mt < 4; ++mt)
            aF[mt] = *(const short8*)&As[(wm + mt * 16 + col) * GK + quad * 8];
        #pragma unroll
        for (int nt = 0; nt < 4; ++nt)
            bF[nt] = *(const short8*)&Bs[(wn + nt * 16 + col) * GK + quad * 8];
        #pragma unroll
        for (int mt = 0; mt < 4; ++mt)
            #pragma unroll
            for (int nt = 0; nt < 4; ++nt)
                acc[mt][nt] = __builtin_amdgcn_mfma_f32_16x16x32_bf16(aF[mt], bF[nt], acc[mt][nt], 0, 0, 0);
    }

    #pragma unroll
    for (int mt = 0; mt < 4; ++mt)
        #pragma unroll
        for (int i = 0; i < 4; ++i) {
            const size_t r = row0 + wm + mt * 16 + quad * 4 + i;
            #pragma unroll
            for (int nt = 0; nt < 4; ++nt) {
                const int c = col0 + wn + nt * 16 + col;
                store_out(&C[r * N + c], (acc[mt][nt][i] + bias[c]) * sc);
            }
        }
}

// ---------------- MFMA flash attention — split-K, fragment-packed K/V -------
// Round-1 skeleton (512 blocks x 4 waves, split-K over 32-key chunks, 64-q
// pair-balanced tiles g/31-g, P-via-LDS, pairwise cross-wave reduction) with
// the ENTIRE K/V LDS staging path deleted: fragments come from kvp via 8
// fully-coalesced dwordx4 per chunk (consecutive 1KB lines), double-buffered
// in registers. Per-chunk chain is now regs->S-MFMA->exp2->P-roundtrip->PV,
// with 4 independent qg chains and next chunk's loads in flight -- no
// store_chunk, no vmcnt/LDS coupling, no staging bank conflicts.
// LDS = P (16 x 640sh, aliased into) reduction buffers (2 x 64x68 f32) = 34.8KB.
// setprio wraps the MFMA/exp cluster (desynced waves: the T5-positive regime).
#define DH 64

__global__ __launch_bounds__(256, 2) void flash_mfma_kernel(
    const short* __restrict__ qkvb,   // bf16 [B,K,3C] (Q pre-scaled)
    const short* __restrict__ kvp,    // fragment-packed K/V
    short* __restrict__ y,            // bf16 [B,K,C]
    int K, int C)
{
    // Or region (2 x 64 x 68 f32 = 34816B) aliases the P region (10240 sh):
    // P is live only during the chunk loop, Or only after the __syncthreads().
    __shared__ __attribute__((aligned(16))) short smem[17408];

    const int tid  = threadIdx.x;
    const int lane = tid & 63, w = tid >> 6;
    const int col  = lane & 15, quad = lane >> 4;

    short* Pw = smem + w * 2560;           // 4 qg bufs x 640 sh, wave-private

    const int cmb = blockIdx.x & 31;       // b*16+h  (XCD-local: idx%8 tracks h)
    const int g   = blockIdx.x >> 5;       // pair index 0..15
    const int b   = cmb >> 4, h = cmb & 15;

    short8 bOnes;                          // L = P @ ones-column = rowsum
    #pragma unroll
    for (int j = 0; j < 8; ++j) bOnes[j] = (col == 0) ? (short)0x3F80 : (short)0;

    const size_t rs = (size_t)3 * C;
    const short* qbase  = qkvb + (size_t)b * K * rs + h * DH;
    const short* kvbase = kvp + (size_t)cmb * 64 * 4096 + lane * 8;

    struct Frag { short8 k[2][2]; short8 v[4]; };
    auto loadF = [&](Frag& f, int ci) {
        const short* p = kvbase + (size_t)ci * 4096;
        f.k[0][0] = *(const short8*)(p);
        f.k[0][1] = *(const short8*)(p + 512);
        f.k[1][0] = *(const short8*)(p + 1024);
        f.k[1][1] = *(const short8*)(p + 1536);
        f.v[0]    = *(const short8*)(p + 2048);
        f.v[1]    = *(const short8*)(p + 2560);
        f.v[2]    = *(const short8*)(p + 3072);
        f.v[3]    = *(const short8*)(p + 3584);
    };

    auto run = [&](int T) {
        const int t0 = T * 64;
        const int NC = 2 * T + 2;          // 32-key chunks in this tile

        short8 aQ[4][2];
        #pragma unroll
        for (int qg = 0; qg < 4; ++qg) {
            const short* qp = qbase + (size_t)(t0 + qg * 16 + col) * rs;
            aQ[qg][0] = *(const short8*)(qp + quad * 8);
            aQ[qg][1] = *(const short8*)(qp + 32 + quad * 8);
        }
        f32x4 O[4][4] = {};
        f32x4 L4[4] = {};

        auto compute = [&](const Frag& f, int ci) {
            const int kc = ci * 32;
            __builtin_amdgcn_s_setprio(1);
            #pragma unroll
            for (int qg = 0; qg < 4; ++qg) {
                const int qb = t0 + qg * 16;
                short* Ptq = Pw + qg * 640;            // private per (wave,qg)
                f32x4 S[2] = {};
                #pragma unroll
                for (int nb = 0; nb < 2; ++nb) {
                    S[nb] = __builtin_amdgcn_mfma_f32_16x16x32_bf16(aQ[qg][0], f.k[nb][0], S[nb], 0, 0, 0);
                    S[nb] = __builtin_amdgcn_mfma_f32_16x16x32_bf16(aQ[qg][1], f.k[nb][1], S[nb], 0, 0, 0);
                }
                if (kc + 31 <= qb) {        // fully unmasked for this q-group
                    #pragma unroll
                    for (int i = 0; i < 4; ++i)
                        *(int*)&Ptq[(quad * 4 + i) * 40 + col * 2] =
                            pack2bf(EXP2(S[0][i]), EXP2(S[1][i]));
                } else {
                    const int kg = kc + col * 2;
                    #pragma unroll
                    for (int i = 0; i < 4; ++i) {
                        const int q = qb + quad * 4 + i;
                        float s0 = (kg + 0 <= q) ? S[0][i] : -INFINITY;
                        float s1 = (kg + 1 <= q) ? S[1][i] : -INFINITY;
                        *(int*)&Ptq[(quad * 4 + i) * 40 + col * 2] =
                            pack2bf(EXP2(s0), EXP2(s1));
                    }
                }
                // compiler inserts the minimal lgkmcnt for this buffer's RAW
                short8 aP = *(const short8*)&Ptq[col * 40 + quad * 8];
                #pragma unroll
                for (int db = 0; db < 4; ++db)
                    O[qg][db] = __builtin_amdgcn_mfma_f32_16x16x32_bf16(aP, f.v[db], O[qg][db], 0, 0, 0);
                L4[qg] = __builtin_amdgcn_mfma_f32_16x16x32_bf16(aP, bOnes, L4[qg], 0, 0, 0);
            }
            __builtin_amdgcn_s_setprio(0);
        };

        // ---- main loop: double-buffered register fragments, prefetch 1 ahead ----
        Frag fA, fB;
        loadF(fA, w);
        for (int ci = w; ci < NC; ci += 8) {
            if (ci + 4 < NC) loadF(fB, ci + 4);
            compute(fA, ci);
            if (ci + 4 < NC) {
                if (ci + 8 < NC) loadF(fA, ci + 8);
                compute(fB, ci + 4);
            }
        }

        // ---- pairwise cross-wave reduction: w0->A, w1->B; w2+=A, w3+=B ----
        float* OrA = (float*)smem;               // 64 x 68 f32
        float* OrB = OrA + 64 * 68;
        __syncthreads();
        if (w < 2) {
            float* R = (w == 0) ? OrA : OrB;
            #pragma unroll
            for (int qg = 0; qg < 4; ++qg)
                #pragma unroll
                for (int i = 0; i < 4; ++i) {
                    const int row = qg * 16 + quad * 4 + i;
                    #pragma unroll
                    for (int db = 0; db < 4; ++db)
                        R[row * 68 + db * 16 + col] = O[qg][db][i];
                    if (col == 0) R[row * 68 + 64] = L4[qg][i];
                }
        }
        __syncthreads();
        if (w >= 2) {
            float* R = (w == 2) ? OrA : OrB;
            #pragma unroll
            for (int qg = 0; qg < 4; ++qg)
                #pragma unroll
                for (int i = 0; i < 4; ++i) {
                    const int row = qg * 16 + quad * 4 + i;
                    #pragma unroll
                    for (int db = 0; db < 4; ++db)
                        R[row * 68 + db * 16 + col] += O[qg][db][i];
                    if (col == 0) R[row * 68 + 64] += L4[qg][i];
                }
        }
        __syncthreads();

        // ---- combine A+B, normalize, store: wave w -> rows [w*16, w*16+16) ----
        #pragma unroll
        for (int rstep = 0; rstep < 4; ++rstep) {
            const int row = w * 16 + rstep * 4 + quad;
            f32x4 oa = *(const f32x4*)&OrA[row * 68 + col * 4];
            f32x4 ob = *(const f32x4*)&OrB[row * 68 + col * 4];
            const float inv = 1.f / (OrA[row * 68 + 64] + OrB[row * 68 + 64]);
            int2v o2 = { pack2bf((oa[0] + ob[0]) * inv, (oa[1] + ob[1]) * inv),
                         pack2bf((oa[2] + ob[2]) * inv, (oa[3] + ob[3]) * inv) };
            *(int2v*)(y + ((size_t)b * K + t0 + row) * C + h * DH + col * 4) = o2;
        }
        __syncthreads();   // protect Or/P alias before next tile's P writes
    };

    run(g);
    run(31 - g);
}

// ------------------------------- launch -------------------------------------
extern "C" void kernel_launch(void* const* d_in, const int* in_sizes, int n_in,
                              void* d_out, int out_size, void* d_ws, size_t ws_size,
                              hipStream_t stream)
{
    const float* x      = (const float*)d_in[0];
    const float* W_qkv  = (const float*)d_in[1];
    const float* b_qkv  = (const float*)d_in[2];
    const float* W_proj = (const float*)d_in[3];
    const float* b_proj = (const float*)d_in[4];

    const int B = 2, K = 2048, C = 1024, H = 16;
    const int M = B * K;   // 4096
    const float C2 = 0.18033688f;   // (1/sqrt(64)) * log2(e)

    char* ws = (char*)d_ws;
    short* xb    = (short*)ws;  ws += (size_t)M * C * 2;
    short* Wt1   = (short*)ws;  ws += (size_t)3 * C * C * 2;
    short* Wt2   = (short*)ws;  ws += (size_t)C * C * 2;
    short* qkvb  = (short*)ws;  ws += (size_t)M * 3 * C * 2;
    short* yb    = (short*)ws;  ws += (size_t)M * C * 2;
    short* kvp   = (short*)ws;  // 32 bh x 64 ci x 8 frag x 512 sh = 16.8 MB

    // prep (fused): cast x + transpose both weights
    const int nbx = (M * C) / 1024;
    const int nb1 = (3 * C / 32) * (C / 32);
    const int nb2 = (C / 32) * (C / 32);
    prep_kernel<<<nbx + nb1 + nb2, 256, 0, stream>>>(x, xb, M * C, W_qkv, Wt1, W_proj, Wt2, C);

    // 1) qkv = x @ W_qkv + b_qkv  (bf16 out; Q columns pre-scaled by C2)
    dim3 g1((3 * C) / GN, M / GM);
    gemm_mfma_kernel<short><<<g1, 256, 0, stream>>>(xb, Wt1, b_qkv, qkvb, M, 3 * C, C, C, C2);

    // 1b) pack K and V into MFMA-fragment-linear order
    dim3 gv(K / 64, H, B);
    kvpack_kernel<<<gv, 256, 0, stream>>>(qkvb, kvp, K, C);

    // 2) flash attention -> yb (bf16); 1-D grid: idx = pair*32 + (b*16+h)
    const int NPAIR = (K / 64) / 2;   // 16
    flash_mfma_kernel<<<dim3(NPAIR * 32), 256, 0, stream>>>(qkvb, kvp, yb, K, C);

    // 3) out = y @ W_proj + b_proj (fp32 out)
    dim3 g3(C / GN, M / GM);
    gemm_mfma_kernel<float><<<g3, 256, 0, stream>>>(yb, Wt2, b_proj, (float*)d_out, M, C, C, 0, 1.f);
}